// Round 10
// baseline (201.634 us; speedup 1.0000x reference)
//
#include <hip/hip_runtime.h>

typedef __attribute__((ext_vector_type(8))) __bf16 bf16x8;
typedef __attribute__((ext_vector_type(4))) float  f32x4;

namespace {
constexpr int kB    = 8192;
constexpr int kTH   = 11;
constexpr int kTP   = 80;
constexpr int kM    = 16;    // rows per tile (MFMA M)
constexpr int kT    = 2;     // tiles per block (ILP + barrier amortization)
constexpr int kStrH = 72;    // H-plane row stride in bf16 units (144 B)
}

union FragU { bf16x8 v; unsigned u[4]; };

__device__ __forceinline__ bf16x8 zero_frag() {
    FragU z; z.u[0] = z.u[1] = z.u[2] = z.u[3] = 0u; return z.v;
}

__device__ __forceinline__ unsigned pack_hi16(unsigned a, unsigned b) {
    return (a >> 16) | (b & 0xFFFF0000u);
}

// fp32[8] -> hi bf16x8 (truncated) + lo bf16x8 (exact remainder, truncated)
__device__ __forceinline__ void split8(const float* f, bf16x8& hi, bf16x8& lo) {
    FragU H, L;
#pragma unroll
    for (int w = 0; w < 4; ++w) {
        const unsigned u0 = __float_as_uint(f[2 * w + 0]);
        const unsigned u1 = __float_as_uint(f[2 * w + 1]);
        const float h0 = __uint_as_float(u0 & 0xFFFF0000u);
        const float h1 = __uint_as_float(u1 & 0xFFFF0000u);
        const unsigned l0 = __float_as_uint(f[2 * w + 0] - h0);
        const unsigned l1 = __float_as_uint(f[2 * w + 1] - h1);
        H.u[w] = pack_hi16(u0, u1);
        L.u[w] = pack_hi16(l0, l1);
    }
    hi = H.v; lo = L.v;
}

// B-fragments (hi/lo) for column `col`: B[k][col] = W[col][k].
__device__ __forceinline__ void loadB1(const float* __restrict__ W, int col, int q,
                                       bf16x8 (&Bh)[2], bf16x8 (&Bl)[2]) {
#pragma unroll
    for (int c = 0; c < 2; ++c) {
        const float* src = W + col * 64 + c * 32 + q * 8;
        const float4 a = reinterpret_cast<const float4*>(src)[0];
        const float4 b = reinterpret_cast<const float4*>(src)[1];
        float f[8] = {a.x, a.y, a.z, a.w, b.x, b.y, b.z, b.w};
        split8(f, Bh[c], Bl[c]);
    }
}

// fc B-fragment: only cols p<2 are real (fcW is 2x64); others zero.
__device__ __forceinline__ void loadBfc(const float* __restrict__ fcW, int p, int q,
                                        bf16x8 (&Bh)[2], bf16x8 (&Bl)[2]) {
#pragma unroll
    for (int c = 0; c < 2; ++c) {
        float f[8];
#pragma unroll
        for (int j = 0; j < 8; ++j)
            f[j] = (p < 2) ? fcW[p * 64 + c * 32 + q * 8 + j] : 0.f;
        split8(f, Bh[c], Bl[c]);
    }
}

// G = w0 (x) fcW[0] + w1 (x) fcW[1]  (rank-2 folded feedback matrix)
__device__ __forceinline__ void loadBG(const float* __restrict__ fcW, float w0, float w1,
                                       int q, bf16x8 (&Bh)[2], bf16x8 (&Bl)[2]) {
#pragma unroll
    for (int c = 0; c < 2; ++c) {
        float f[8];
#pragma unroll
        for (int j = 0; j < 8; ++j) {
            const int k = c * 32 + q * 8 + j;
            f[j] = w0 * fcW[k] + w1 * fcW[64 + k];
        }
        split8(f, Bh[c], Bl[c]);
    }
}

// split h into hi/lo bf16 and store to the two planes
__device__ __forceinline__ void write_h(unsigned short* hi, unsigned short* lo,
                                        int idx, float h) {
    const unsigned u = __float_as_uint(h);
    hi[idx] = (unsigned short)(u >> 16);
    const float hf = __uint_as_float(u & 0xFFFF0000u);
    const float l  = h - hf;                        // exact
    lo[idx] = (unsigned short)(__float_as_uint(l) >> 16);
}

__device__ __forceinline__ bf16x8 read_frag(const unsigned short* plane, int off) {
    return *reinterpret_cast<const bf16x8*>(plane + off);
}

// 3-term Markidis accumulate: D += Ah*Bh + Ah*Bl + Al*Bh
__device__ __forceinline__ f32x4 mfma3(bf16x8 ah, bf16x8 al, bf16x8 bh, bf16x8 bl, f32x4 acc) {
    acc = __builtin_amdgcn_mfma_f32_16x16x32_bf16(ah, bh, acc, 0, 0, 0);
    acc = __builtin_amdgcn_mfma_f32_16x16x32_bf16(ah, bl, acc, 0, 0, 0);
    acc = __builtin_amdgcn_mfma_f32_16x16x32_bf16(al, bh, acc, 0, 0, 0);
    return acc;
}

// tanh via raw v_exp/v_rcp: 1 - 2*rcp(2^(2*log2e*x)+1); saturates safely.
__device__ __forceinline__ float fast_tanh(float x) {
    const float e = __builtin_amdgcn_exp2f(x * 2.8853900817779268f);  // 2/ln2
    return fmaf(-2.0f, __builtin_amdgcn_rcpf(e + 1.0f), 1.0f);
}

// 1024 waves on 1024 SIMDs -> 1 wave/SIMD; give the allocator the full budget.
__global__ __attribute__((amdgpu_waves_per_eu(1, 1))) __launch_bounds__(256)
void traj_rnn_kernel(
    const float* __restrict__ x,
    const float* __restrict__ eWih0, const float* __restrict__ eWhh0,
    const float* __restrict__ ebih0, const float* __restrict__ ebhh0,
    const float* __restrict__ eWih1, const float* __restrict__ eWhh1,
    const float* __restrict__ ebih1, const float* __restrict__ ebhh1,
    const float* __restrict__ dWih0, const float* __restrict__ dWhh0,
    const float* __restrict__ dbih0, const float* __restrict__ dbhh0,
    const float* __restrict__ dWih1, const float* __restrict__ dWhh1,
    const float* __restrict__ dbih1, const float* __restrict__ dbhh1,
    const float* __restrict__ fcW, const float* __restrict__ fcb,
    float* __restrict__ out)
{
    const int tid  = threadIdx.x;
    const int wv   = tid >> 6;          // n-tile owned by this wave (0..3)
    const int lane = tid & 63;
    const int p    = lane & 15;         // A-m / C-col-within-tile
    const int q    = lane >> 4;         // k-quad / C row-quad
    const int col  = wv * 16 + p;       // this lane's hidden-unit column
    const int r0   = blockIdx.x * (kT * kM);

    __shared__ __align__(16) unsigned short Hhi1[kT][kM * kStrH], Hlo1[kT][kM * kStrH];
    __shared__ __align__(16) unsigned short Hhi2[kT][kM * kStrH], Hlo2[kT][kM * kStrH];
    __shared__ __align__(16) float xbuf[kT * kM * kTH * 2];

    for (int i = tid; i < kT * kM * kTH * 2; i += 256)
        xbuf[i] = x[r0 * (kTH * 2) + i];

    bf16x8 H1h[kT][2], H1l[kT][2], H2h[kT][2], H2l[kT][2];
#pragma unroll
    for (int u = 0; u < kT; ++u)
#pragma unroll
        for (int c = 0; c < 2; ++c) {
            H1h[u][c] = zero_frag(); H1l[u][c] = zero_frag();
            H2h[u][c] = zero_frag(); H2l[u][c] = zero_frag();
        }
    __syncthreads();

    const int aoff = p * kStrH;  // A-fragment base for this lane's m-row

    // ================= encoder: 11 steps =================
    {
        const float b0 = ebih0[col] + ebhh0[col];
        const float b1 = ebih1[col] + ebhh1[col];
        const float w0 = eWih0[col * 2 + 0];
        const float w1 = eWih0[col * 2 + 1];
        bf16x8 B0h[2], B0l[2], B1h[2], B1l[2], B2h[2], B2l[2];
        loadB1(eWhh0, col, q, B0h, B0l);   // Whh0
        loadB1(eWih1, col, q, B1h, B1l);   // Wih1
        loadB1(eWhh1, col, q, B2h, B2l);   // Whh1

        f32x4 P1[kT];
#pragma unroll
        for (int u = 0; u < kT; ++u) P1[u] = {b0, b0, b0, b0};

#pragma unroll 1
        for (int t = 0; t < kTH; ++t) {
#pragma unroll
            for (int u = 0; u < kT; ++u)
#pragma unroll
                for (int r = 0; r < 4; ++r) {
                    const float2 xv = *reinterpret_cast<const float2*>(
                        &xbuf[(u * kM + 4 * q + r) * (kTH * 2) + 2 * t]);
                    const float h1 = fast_tanh(fmaf(w0, xv.x, fmaf(w1, xv.y, P1[u][r])));
                    write_h(Hhi1[u], Hlo1[u], (4 * q + r) * kStrH + col, h1);
                }
            // layer-2 partial on OLD H2 before the barrier
            f32x4 a2[kT];
#pragma unroll
            for (int u = 0; u < kT; ++u) {
                a2[u] = {b1, b1, b1, b1};
#pragma unroll
                for (int c = 0; c < 2; ++c)
                    a2[u] = mfma3(H2h[u][c], H2l[u][c], B2h[c], B2l[c], a2[u]);
            }
            __syncthreads();   // h1' visible

#pragma unroll
            for (int u = 0; u < kT; ++u)
#pragma unroll
                for (int c = 0; c < 2; ++c) {
                    H1h[u][c] = read_frag(Hhi1[u], aoff + c * 32 + q * 8);
                    H1l[u][c] = read_frag(Hlo1[u], aoff + c * 32 + q * 8);
                }
#pragma unroll
            for (int u = 0; u < kT; ++u) {
#pragma unroll
                for (int c = 0; c < 2; ++c)
                    a2[u] = mfma3(H1h[u][c], H1l[u][c], B1h[c], B1l[c], a2[u]);
                f32x4 np = {b0, b0, b0, b0};
#pragma unroll
                for (int c = 0; c < 2; ++c)
                    np = mfma3(H1h[u][c], H1l[u][c], B0h[c], B0l[c], np);
                P1[u] = np;
#pragma unroll
                for (int r = 0; r < 4; ++r) {
                    const float h2 = fast_tanh(a2[u][r]);
                    write_h(Hhi2[u], Hlo2[u], (4 * q + r) * kStrH + col, h2);
                }
            }
            __syncthreads();   // h2' visible
#pragma unroll
            for (int u = 0; u < kT; ++u)
#pragma unroll
                for (int c = 0; c < 2; ++c) {
                    H2h[u][c] = read_frag(Hhi2[u], aoff + c * 32 + q * 8);
                    H2l[u][c] = read_frag(Hlo2[u], aoff + c * 32 + q * 8);
                }
        }
    }

    // ================= decoder: 80 autoregressive steps =================
    {
        const float b0 = dbih0[col] + dbhh0[col];
        const float b1 = dbih1[col] + dbhh1[col];
        const float w0 = dWih0[col * 2 + 0];
        const float w1 = dWih0[col * 2 + 1];
        const float fb0 = fcb[0];
        const float fb1 = fcb[1];
        const float b0p = b0 + w0 * fb0 + w1 * fb1;  // folded feedback bias
        const float fbp = (p == 0) ? fb0 : fb1;
        bf16x8 B0h[2], B0l[2], B1h[2], B1l[2], B2h[2], B2l[2];
        bf16x8 BFh[2], BFl[2], BGh[2], BGl[2];
        loadB1(dWhh0, col, q, B0h, B0l);
        loadB1(dWih1, col, q, B1h, B1l);
        loadB1(dWhh1, col, q, B2h, B2l);
        loadBfc(fcW, p, q, BFh, BFl);
        loadBG(fcW, w0, w1, q, BGh, BGl);   // rank-2 folded feedback matrix

        // P1 for the FIRST decoder step per tile
        f32x4 P1[kT];
#pragma unroll
        for (int u = 0; u < kT; ++u) {
            f32x4 a = {b0, b0, b0, b0};
#pragma unroll
            for (int c = 0; c < 2; ++c)
                a = mfma3(H1h[u][c], H1l[u][c], B0h[c], B0l[c], a);
#pragma unroll
            for (int r = 0; r < 4; ++r) {
                const float2 xv = *reinterpret_cast<const float2*>(
                    &xbuf[(u * kM + 4 * q + r) * (kTH * 2) + 2 * (kTH - 1)]);
                a[r] = fmaf(w0, xv.x, fmaf(w1, xv.y, a[r]));
            }
            P1[u] = a;
        }

#pragma unroll 1
        for (int t = 0; t < kTP; ++t) {
#pragma unroll
            for (int u = 0; u < kT; ++u)
#pragma unroll
                for (int r = 0; r < 4; ++r) {
                    const float h1 = fast_tanh(P1[u][r]);
                    write_h(Hhi1[u], Hlo1[u], (4 * q + r) * kStrH + col, h1);
                }
            f32x4 a2[kT];
#pragma unroll
            for (int u = 0; u < kT; ++u) {
                a2[u] = {b1, b1, b1, b1};
#pragma unroll
                for (int c = 0; c < 2; ++c)
                    a2[u] = mfma3(H2h[u][c], H2l[u][c], B2h[c], B2l[c], a2[u]);
            }
            __syncthreads();   // h1' visible

#pragma unroll
            for (int u = 0; u < kT; ++u)
#pragma unroll
                for (int c = 0; c < 2; ++c) {
                    H1h[u][c] = read_frag(Hhi1[u], aoff + c * 32 + q * 8);
                    H1l[u][c] = read_frag(Hlo1[u], aoff + c * 32 + q * 8);
                }
            f32x4 np[kT];
#pragma unroll
            for (int u = 0; u < kT; ++u) {
#pragma unroll
                for (int c = 0; c < 2; ++c)
                    a2[u] = mfma3(H1h[u][c], H1l[u][c], B1h[c], B1l[c], a2[u]);
                np[u] = {b0p, b0p, b0p, b0p};
#pragma unroll
                for (int c = 0; c < 2; ++c)
                    np[u] = mfma3(H1h[u][c], H1l[u][c], B0h[c], B0l[c], np[u]);
#pragma unroll
                for (int r = 0; r < 4; ++r) {
                    const float h2 = fast_tanh(a2[u][r]);
                    write_h(Hhi2[u], Hlo2[u], (4 * q + r) * kStrH + col, h2);
                }
            }
            __syncthreads();   // h2' visible

#pragma unroll
            for (int u = 0; u < kT; ++u)
#pragma unroll
                for (int c = 0; c < 2; ++c) {
                    H2h[u][c] = read_frag(Hhi2[u], aoff + c * 32 + q * 8);
                    H2l[u][c] = read_frag(Hlo2[u], aoff + c * 32 + q * 8);
                }
#pragma unroll
            for (int u = 0; u < kT; ++u) {
#pragma unroll
                for (int c = 0; c < 2; ++c)
                    np[u] = mfma3(H2h[u][c], H2l[u][c], BGh[c], BGl[c], np[u]);
                P1[u] = np[u];
            }

            // pred output only on wave 0 (wave-uniform branch)
            if (wv == 0) {
#pragma unroll
                for (int u = 0; u < kT; ++u) {
                    f32x4 fcC = {0.f, 0.f, 0.f, 0.f};
#pragma unroll
                    for (int c = 0; c < 2; ++c)
                        fcC = mfma3(H2h[u][c], H2l[u][c], BFh[c], BFl[c], fcC);
                    if (p < 2) {
#pragma unroll
                        for (int r = 0; r < 4; ++r)
                            out[((r0 + u * kM + 4 * q + r) * kTP + t) * 2 + p] = fcC[r] + fbp;
                    }
                }
            }
        }
    }
}

extern "C" void kernel_launch(void* const* d_in, const int* in_sizes, int n_in,
                              void* d_out, int out_size, void* d_ws, size_t ws_size,
                              hipStream_t stream) {
    const float* x     = (const float*)d_in[0];
    const float* eWih0 = (const float*)d_in[1];
    const float* eWhh0 = (const float*)d_in[2];
    const float* ebih0 = (const float*)d_in[3];
    const float* ebhh0 = (const float*)d_in[4];
    const float* eWih1 = (const float*)d_in[5];
    const float* eWhh1 = (const float*)d_in[6];
    const float* ebih1 = (const float*)d_in[7];
    const float* ebhh1 = (const float*)d_in[8];
    const float* dWih0 = (const float*)d_in[9];
    const float* dWhh0 = (const float*)d_in[10];
    const float* dbih0 = (const float*)d_in[11];
    const float* dbhh0 = (const float*)d_in[12];
    const float* dWih1 = (const float*)d_in[13];
    const float* dWhh1 = (const float*)d_in[14];
    const float* dbih1 = (const float*)d_in[15];
    const float* dbhh1 = (const float*)d_in[16];
    const float* fcW   = (const float*)d_in[17];
    const float* fcb   = (const float*)d_in[18];
    float* out = (float*)d_out;

    dim3 grid(kB / (kT * kM));  // 256 blocks x 4 waves; 2 row-tiles per block
    dim3 block(256);
    traj_rnn_kernel<<<grid, block, 0, stream>>>(
        x, eWih0, eWhh0, ebih0, ebhh0, eWih1, eWhh1, ebih1, ebhh1,
        dWih0, dWhh0, dbih0, dbhh0, dWih1, dWhh1, dbih1, dbhh1,
        fcW, fcb, out);
}